// Round 13
// baseline (466.287 us; speedup 1.0000x reference)
//
#include <hip/hip_runtime.h>

#define NN 128   // points per set
#define NB 128   // batches
#define ND 5     // feature dim
#define INFV 3.4028235e38f

__device__ __forceinline__ float wrap_phi(float x) {
  const float PI_F   = 3.14159265358979323846f;
  const float TWO_PI = 6.28318530717958647692f;
  float t = x + PI_F;
  float w = t - floorf(t * (1.0f / TWO_PI)) * TWO_PI;  // jnp.remainder semantics
  return w - PI_F;
}

// DPP fetch with +INF for masked-out/invalid lanes (no-op under fmin)
#define DPP_SRC_INF(x, ctrl, rmask)                                           \
  __int_as_float(__builtin_amdgcn_update_dpp(                                 \
      0x7f800000, __float_as_int(x), (ctrl), (rmask), 0xF, false))

#define DPP_MIN_STEP(x, ctrl, rmask) x = fminf(x, DPP_SRC_INF(x, ctrl, rmask))

// paired (min1,min2) merge step: {x1,x2} <- merge({x1,x2},{partner})
#define DPP_MIN2_STEP(x1, x2, ctrl, rmask)                                    \
  { float _a1 = DPP_SRC_INF(x1, ctrl, rmask);                                 \
    float _a2 = DPP_SRC_INF(x2, ctrl, rmask);                                 \
    float _t  = fmaxf(x1, _a1);                                               \
    x1 = fminf(x1, _a1);                                                      \
    x2 = fminf(fminf(x2, _a2), _t); }

__device__ __forceinline__ int rl_i(int v, int lane) {
  return __builtin_amdgcn_readlane(v, lane);
}
__device__ __forceinline__ float rl_f(float v, int lane) {
  return __int_as_float(__builtin_amdgcn_readlane(__float_as_int(v), lane));
}

__device__ __forceinline__ float wave_min_bcast(float x) {
  DPP_MIN_STEP(x, 0xB1,  0xF);  // quad_perm xor 1
  DPP_MIN_STEP(x, 0x4E,  0xF);  // quad_perm xor 2
  DPP_MIN_STEP(x, 0x141, 0xF);  // row_half_mirror
  DPP_MIN_STEP(x, 0x140, 0xF);  // row_mirror
  DPP_MIN_STEP(x, 0x142, 0xA);  // row_bcast15
  DPP_MIN_STEP(x, 0x143, 0xC);  // row_bcast31 (lane 63 = full min)
  return rl_f(x, 63);
}

// (min1, min2) over all 128 per-lane-pair values; broadcast from lane 63.
// x1-path is the same fminf chain as wave_min_bcast -> min1 bit-identical.
__device__ __forceinline__ void wave_min2_bcast(float &x1, float &x2) {
  DPP_MIN2_STEP(x1, x2, 0xB1,  0xF);
  DPP_MIN2_STEP(x1, x2, 0x4E,  0xF);
  DPP_MIN2_STEP(x1, x2, 0x141, 0xF);
  DPP_MIN2_STEP(x1, x2, 0x140, 0xF);
  DPP_MIN2_STEP(x1, x2, 0x142, 0xA);
  DPP_MIN2_STEP(x1, x2, 0x143, 0xC);
  x1 = rl_f(x1, 63);
  x2 = rl_f(x2, 63);
}

// One block (64 threads = 1 wave) solves one batch's 128x128 assignment:
// LAPJV init (column reduction fused into cost build + 2-wide Jacobi
// reduction transfer + 8-pass bounded augmenting row reduction) + lazy
// single-source Dijkstra with RUNNER-UP ROW SPECULATION: the matched row of
// the global min2 column is prefetched each extraction (p[] is frozen during
// a search, so the data stays valid); on a correct guess the next iteration
// skips its ds_read (~240cy -> ~140cy chain).
__global__ __launch_bounds__(64) void set2set_hungarian(
    const float* __restrict__ inp, const float* __restrict__ tgt,
    float* __restrict__ sums)
{
  const int b = blockIdx.x;
  const int lane = threadIdx.x;

  __shared__ __align__(16) float Csh[NN * NN]; // cost matrix, row-major, 64 KB
  __shared__ float inpS[NN * ND];              // staged input rows
  __shared__ int   rowOwner[NN + 1];           // CR arbitration
  __shared__ float uFree[NN + 1];              // u[] of rows freed by steals

  const float* inB = inp + (size_t)b * NN * ND;
  const float* tgB = tgt + (size_t)b * NN * ND;

  for (int idx = lane; idx < NN * ND; idx += 64) inpS[idx] = inB[idx];
  for (int idx = lane; idx <= NN; idx += 64) { rowOwner[idx] = 0x7fffffff; uFree[idx] = 0.f; }
  __syncthreads();

  // this lane owns 0-indexed columns jA, jB  (1-indexed c1A, c1B)
  const int jA = 2 * lane;
  const int jB = 2 * lane + 1;
  const int c1A = jA + 1, c1B = jB + 1;

  float tA[ND], tB[ND];
  #pragma unroll
  for (int d = 0; d < ND; ++d) { tA[d] = tgB[jA * ND + d]; tB[d] = tgB[jB * ND + d]; }

  // build cost matrix C[i][j] = ||input_i - target_j||, fused column-min (CR)
  float vA = INFV, vB = INFV;  // column duals = column min
  int   rmA = 1,  rmB = 1;     // argmin row (first occurrence, 1-indexed)
  #pragma unroll 4
  for (int i = 0; i < NN; ++i) {
    float sA = 0.f, sB = 0.f;
    #pragma unroll
    for (int d = 0; d < ND; ++d) {
      float x = inpS[i * ND + d];
      float da = x - tA[d]; sA = fmaf(da, da, sA);
      float db = x - tB[d]; sB = fmaf(db, db, sB);
    }
    float cA = sqrtf(sA), cB = sqrtf(sB);
    ((float2*)(Csh + i * NN))[lane] = make_float2(cA, cB);
    if (cA < vA) { vA = cA; rmA = i + 1; }
    if (cB < vB) { vB = cB; rmB = i + 1; }
  }
  __syncthreads();

  // ---- column reduction: greedy match argmin rows, lowest column wins ----
  atomicMin(&rowOwner[rmA], c1A);
  atomicMin(&rowOwner[rmB], c1B);
  __syncthreads();

  int   pA = (rowOwner[rmA] == c1A) ? rmA : 0;  // matched row per column, 0 = free
  int   pB = (rowOwner[rmB] == c1B) ? rmB : 0;
  float uA = 0.f, uB = 0.f;   // dual of the row matched to col A/B
  int   wayA = 0, wayB = 0;

  // ---- reduction transfer (Jacobi, 2-wide paired reads) ----
  {
    const float vOldA = vA, vOldB = vB;
    unsigned long long mtA = __ballot(pA != 0);
    unsigned long long mtB = __ballot(pB != 0);
    while (mtA | mtB) {
      int l1, s1;
      if (mtA) { l1 = __ffsll(mtA) - 1; mtA &= mtA - 1ull; s1 = 0; }
      else     { l1 = __ffsll(mtB) - 1; mtB &= mtB - 1ull; s1 = 1; }
      int i1 = rl_i(s1 ? pB : pA, l1);
      int l2 = -1, s2 = 0, i2 = 0;
      if (mtA)      { l2 = __ffsll(mtA) - 1; mtA &= mtA - 1ull; s2 = 0; }
      else if (mtB) { l2 = __ffsll(mtB) - 1; mtB &= mtB - 1ull; s2 = 1; }
      if (l2 >= 0) i2 = rl_i(s2 ? pB : pA, l2);

      const float2 c1 = ((const float2*)(Csh + (i1 - 1) * NN))[lane];
      float2 c2 = make_float2(0.f, 0.f);
      if (i2) c2 = ((const float2*)(Csh + (i2 - 1) * NN))[lane];

      float r1A = c1.x - vOldA, r1B = c1.y - vOldB;
      if (lane == l1) { if (s1) r1B = INFV; else r1A = INFV; }  // exclude j1
      float mu1 = wave_min_bcast(fminf(r1A, r1B));
      bool e1A = (lane == l1) && (s1 == 0);
      bool e1B = (lane == l1) && (s1 == 1);
      vA -= e1A ? mu1 : 0.f;   vB -= e1B ? mu1 : 0.f;
      uA  = e1A ? mu1 : uA;    uB  = e1B ? mu1 : uB;

      if (i2) {
        float r2A = c2.x - vOldA, r2B = c2.y - vOldB;
        if (lane == l2) { if (s2) r2B = INFV; else r2A = INFV; }
        float mu2 = wave_min_bcast(fminf(r2A, r2B));
        bool e2A = (lane == l2) && (s2 == 0);
        bool e2B = (lane == l2) && (s2 == 1);
        vA -= e2A ? mu2 : 0.f;   vB -= e2B ? mu2 : 0.f;
        uA  = e2A ? mu2 : uA;    uB  = e2B ? mu2 : uB;
      }
    }
  }

  // free rows after CR
  unsigned long long remLo = __ballot(rowOwner[1 + lane]  == 0x7fffffff);
  unsigned long long remHi = __ballot(rowOwner[65 + lane] == 0x7fffffff);

  // ---- augmenting row reduction: 8 bounded passes (no within-pass retry) ----
  #pragma unroll 1
  for (int pass = 0; pass < 8; ++pass) {
    unsigned long long inLo = remLo, inHi = remHi;
    unsigned long long outLo = 0ull, outHi = 0ull;
    while (inLo | inHi) {
      int i;
      if (inLo) { int t = __ffsll(inLo) - 1; inLo &= inLo - 1ull; i = t + 1; }
      else      { int t = __ffsll(inHi) - 1; inHi &= inHi - 1ull; i = t + 65; }

      const float2 c = ((const float2*)(Csh + (i - 1) * NN))[lane];
      float rcA = c.x - vA, rcB = c.y - vB;      // reduced costs
      float m1 = fminf(rcA, rcB), m2 = fmaxf(rcA, rcB);
      float candv = m1;
      bool  aMin  = (rcA <= rcB);                // prefer lower column on tie
      int   candc = aMin ? c1A : c1B;
      int   candp = aMin ? pA : pB;
      float candu = aMin ? uA : uB;
      wave_min2_bcast(m1, m2);                   // global (min1, min2)

      unsigned long long msk = __ballot(candv == m1);
      int l = __ffsll(msk) - 1;                  // lowest lane = lowest column
      int   j1   = rl_i(candc, l);               // three parallel readlanes
      int   i0   = rl_i(candp, l);
      float uOld = rl_f(candu, l);
      int owner = l, slot = (j1 - 1) & 1;

      float dv = m2 - m1;                        // >= 0
      bool selA = (lane == owner) && (slot == 0);
      bool selB = (lane == owner) && (slot == 1);
      vA -= selA ? dv : 0.f;   vB -= selB ? dv : 0.f;
      pA  = selA ? i  : pA;    pB  = selB ? i  : pB;
      uA  = selA ? m2 : uA;    uB  = selB ? m2 : uB;

      if (i0 != 0) {                             // stolen row -> next phase
        if (lane == 0) uFree[i0] = uOld;
        if (i0 <= 64) outLo |= 1ull << (i0 - 1);
        else          outHi |= 1ull << (i0 - 65);
      }
    }
    remLo = outLo; remHi = outHi;
  }
  unsigned long long dijLo = remLo, dijHi = remHi;

  // ---- LAZY Dijkstra with runner-up row speculation ----
  while (dijLo | dijHi) {
    int i;
    if (dijLo) { int t = __ffsll(dijLo) - 1; dijLo &= dijLo - 1ull; i = t + 1; }
    else       { int t = __ffsll(dijHi) - 1; dijHi &= dijHi - 1ull; i = t + 65; }
    float uf = uFree[i];

    float dLiveA = INFV, dLiveB = INFV;  // INF once extracted
    float dFrzA = 0.f, dFrzB = 0.f;      // frozen distance at extraction
    bool usedA = false, usedB = false;
    int   j0 = 0, i0 = i;
    float minVal = 0.f;
    float tshift = 0.f - uf;
    float tvA = tshift - vA, tvB = tshift - vB; // off-chain fold
    int   jfree = 0;
    int   specJ = -1;                    // speculated next column (-1 = none)
    float2 specRow = make_float2(0.f, 0.f);

    for (int guard = 0; guard <= NN + 1; ++guard) {
      float2 c;
      if (j0 == specJ) {
        c = specRow;                     // spec hit: no ds_read on the chain
      } else {
        c = ((const float2*)(Csh + (i0 - 1) * NN))[lane];
      }
      float curA = c.x + tvA;                   // 1 op after the data
      float curB = c.y + tvB;
      float curMA = usedA ? INFV : curA;        // used-mask known early
      float curMB = usedB ? INFV : curB;
      bool okA = curMA < dLiveA;                // way cmp, parallel w/ fmin
      bool okB = curMB < dLiveB;
      wayA = okA ? j0 : wayA;
      wayB = okB ? j0 : wayB;
      dLiveA = fminf(dLiveA, curMA);            // no cmp->sel dependency
      dLiveB = fminf(dLiveB, curMB);

      float m1l = fminf(dLiveA, dLiveB);        // per-lane sorted pair
      float m2l = fmaxf(dLiveA, dLiveB);
      bool  aMin   = (dLiveA <= dLiveB);        // prefer lower column on tie
      int   candc  = aMin ? c1A : c1B;
      int   candcO = aMin ? c1B : c1A;          // runner side column
      int   candp  = aMin ? pA : pB;
      float candu  = aMin ? uA : uB;

      float r1 = m1l, r2 = m2l;
      wave_min2_bcast(r1, r2);                  // r1 = min (bit-identical), r2 = min2
      minVal = r1;
      unsigned long long msk = __ballot(m1l == minVal);
      int l = __ffsll(msk) - 1;
      int   j1  = rl_i(candc, l);               // parallel readlanes
      int   pj1 = rl_i(candp, l);
      float uj  = rl_f(candu, l);
      if (pj1 == 0) { jfree = j1; break; }

      bool nowA = (j1 == c1A), nowB = (j1 == c1B);
      usedA |= nowA;  usedB |= nowB;
      dFrzA = nowA ? minVal : dFrzA;            // freeze; hidden under read
      dFrzB = nowB ? minVal : dFrzB;
      dLiveA = nowA ? INFV : dLiveA;
      dLiveB = nowB ? INFV : dLiveB;
      tshift = minVal - uj;
      tvA = tshift - vA;  tvB = tshift - vB;    // hidden under next ds_read
      j0 = j1; i0 = pj1;

      // ---- speculate: next winner = global runner-up column (min2) ----
      // p[] is frozen during the search, so the prefetched row stays valid.
      specJ = -1;
      if (r2 < INFV) {
        unsigned long long g1 = __ballot(m1l == r2) & ~(1ull << l);
        unsigned long long g2 = __ballot(m2l == r2);
        int jg = 0;
        if (g1)      { int lg = __ffsll(g1) - 1; jg = rl_i(candc,  lg); }
        else if (g2) { int lg = __ffsll(g2) - 1; jg = rl_i(candcO, lg); }
        if (jg == j1) jg = 0;
        if (jg) {
          int og = (jg - 1) >> 1, sg = (jg - 1) & 1;
          int pg = rl_i(sg ? pB : pA, og);
          if (pg != 0) {                        // free column would end search
            specJ = jg;
            specRow = ((const float2*)(Csh + (pg - 1) * NN))[lane];
          }
        }
      }
    }

    // vectorized dual update for extracted columns (pre-augmentation)
    {
      float adjA = dFrzA - minVal;              // <= 0 for used columns
      float adjB = dFrzB - minVal;
      vA += usedA ? adjA : 0.f;   uA -= usedA ? adjA : 0.f;
      vB += usedB ? adjB : 0.f;   uB -= usedB ? adjB : 0.f;
    }
    float ucur = uf + minVal;                   // new dual of the start row

    // augment along way[] chain; transfer row + its dual between columns
    int jj = jfree;
    for (int g = 0; g < NN + 1 && jj != 0; ++g) {
      int owner = (jj - 1) >> 1, slot = (jj - 1) & 1;
      int wj = slot ? rl_i(wayB, owner) : rl_i(wayA, owner);
      int pnew; float unew;
      if (wj == 0) { pnew = i; unew = ucur; }
      else {
        int o2 = (wj - 1) >> 1, s2 = (wj - 1) & 1;
        pnew = s2 ? rl_i(pB, o2) : rl_i(pA, o2);
        unew = s2 ? rl_f(uB, o2) : rl_f(uA, o2);
      }
      bool selA = (lane == owner) && (slot == 0);
      bool selB = (lane == owner) && (slot == 1);
      pA = selA ? pnew : pA;  uA = selA ? unew : uA;
      pB = selB ? pnew : pB;  uB = selB ? unew : uB;
      jj = wj;
    }
  }

  // loss: column j (0-idx) is matched to row r = p-1; d = input[r] - target[j]
  int rA = pA - 1;
  int rB = pB - 1;
  float acc[ND];
  #pragma unroll
  for (int d = 0; d < ND; ++d) {
    float dA = inpS[rA * ND + d] - tA[d];
    float dB = inpS[rB * ND + d] - tB[d];
    if (d == 4) { dA = wrap_phi(dA); dB = wrap_phi(dB); }
    acc[d] = dA * dA + dB * dB;
  }
  #pragma unroll
  for (int d = 0; d < ND; ++d) {
    float s = acc[d];
    #pragma unroll
    for (int off = 32; off > 0; off >>= 1) s += __shfl_xor(s, off);
    if (lane == 0) atomicAdd(&sums[d], s);
  }
}

__global__ void set2set_finalize(const float* __restrict__ sums, float* __restrict__ out) {
  const float inv = 1.0f / (128.0f * 128.0f);
  float x  = sums[0] * inv;
  float y  = sums[1] * inv;
  float E  = sums[2] * inv;
  float th = sums[3] * inv;
  float ph = sums[4] * inv;
  out[1] = x; out[2] = y; out[3] = E; out[4] = th; out[5] = ph;
  out[0] = x + y + E + th + ph;
}

extern "C" void kernel_launch(void* const* d_in, const int* in_sizes, int n_in,
                              void* d_out, int out_size, void* d_ws, size_t ws_size,
                              hipStream_t stream) {
  const float* inp = (const float*)d_in[0];
  const float* tgt = (const float*)d_in[1];
  float* out  = (float*)d_out;
  float* sums = (float*)d_ws;

  hipMemsetAsync(sums, 0, ND * sizeof(float), stream);
  set2set_hungarian<<<dim3(NB), dim3(64), 0, stream>>>(inp, tgt, sums);
  set2set_finalize<<<dim3(1), dim3(1), 0, stream>>>(sums, out);
}

// Round 14
// 371.157 us; speedup vs baseline: 1.2563x; 1.2563x over previous
//
#include <hip/hip_runtime.h>

#define NN 128   // points per set
#define NB 128   // batches
#define ND 5     // feature dim
#define INFV 3.4028235e38f

__device__ __forceinline__ float wrap_phi(float x) {
  const float PI_F   = 3.14159265358979323846f;
  const float TWO_PI = 6.28318530717958647692f;
  float t = x + PI_F;
  float w = t - floorf(t * (1.0f / TWO_PI)) * TWO_PI;  // jnp.remainder semantics
  return w - PI_F;
}

// DPP fetch with +INF for masked-out/invalid lanes (no-op under fmin)
#define DPP_SRC_INF(x, ctrl, rmask)                                           \
  __int_as_float(__builtin_amdgcn_update_dpp(                                 \
      0x7f800000, __float_as_int(x), (ctrl), (rmask), 0xF, false))

#define DPP_MIN_STEP(x, ctrl, rmask) x = fminf(x, DPP_SRC_INF(x, ctrl, rmask))

// paired (min1,min2) merge step: {x1,x2} <- merge({x1,x2},{partner})
#define DPP_MIN2_STEP(x1, x2, ctrl, rmask)                                    \
  { float _a1 = DPP_SRC_INF(x1, ctrl, rmask);                                 \
    float _a2 = DPP_SRC_INF(x2, ctrl, rmask);                                 \
    float _t  = fmaxf(x1, _a1);                                               \
    x1 = fminf(x1, _a1);                                                      \
    x2 = fminf(fminf(x2, _a2), _t); }

__device__ __forceinline__ int rl_i(int v, int lane) {
  return __builtin_amdgcn_readlane(v, lane);
}
__device__ __forceinline__ float rl_f(float v, int lane) {
  return __int_as_float(__builtin_amdgcn_readlane(__float_as_int(v), lane));
}

__device__ __forceinline__ float wave_min_bcast(float x) {
  DPP_MIN_STEP(x, 0xB1,  0xF);  // quad_perm xor 1
  DPP_MIN_STEP(x, 0x4E,  0xF);  // quad_perm xor 2
  DPP_MIN_STEP(x, 0x141, 0xF);  // row_half_mirror
  DPP_MIN_STEP(x, 0x140, 0xF);  // row_mirror
  DPP_MIN_STEP(x, 0x142, 0xA);  // row_bcast15
  DPP_MIN_STEP(x, 0x143, 0xC);  // row_bcast31 (lane 63 = full min)
  return rl_f(x, 63);
}

// (min1, min2) over all 128 per-lane-pair values; broadcast from lane 63
__device__ __forceinline__ void wave_min2_bcast(float &x1, float &x2) {
  DPP_MIN2_STEP(x1, x2, 0xB1,  0xF);
  DPP_MIN2_STEP(x1, x2, 0x4E,  0xF);
  DPP_MIN2_STEP(x1, x2, 0x141, 0xF);
  DPP_MIN2_STEP(x1, x2, 0x140, 0xF);
  DPP_MIN2_STEP(x1, x2, 0x142, 0xA);
  DPP_MIN2_STEP(x1, x2, 0x143, 0xC);
  x1 = rl_f(x1, 63);
  x2 = rl_f(x2, 63);
}

// One block (64 threads = 1 wave) solves one batch's 128x128 assignment:
// LAPJV init (column reduction fused into cost build + 2-wide Jacobi
// reduction transfer + 6-pass bounded augmenting row reduction) + lazy
// single-source Dijkstra augmentation. State register-resident; cross-lane
// via DPP/readlane/ballot. This is the measured optimum of the session
// (316 us rocprof); r10 multi-source, r12 micro-shaves, r13 speculation all
// regressed or were neutral -> structural serial-latency floor:
// ~2800 extractions x ~240cy (ds_read 120 + DPP reduce 56 + ballot/readlane).
__global__ __launch_bounds__(64) void set2set_hungarian(
    const float* __restrict__ inp, const float* __restrict__ tgt,
    float* __restrict__ sums)
{
  const int b = blockIdx.x;
  const int lane = threadIdx.x;

  __shared__ __align__(16) float Csh[NN * NN]; // cost matrix, row-major, 64 KB
  __shared__ float inpS[NN * ND];              // staged input rows
  __shared__ int   rowOwner[NN + 1];           // CR arbitration
  __shared__ float uFree[NN + 1];              // u[] of rows freed by steals

  const float* inB = inp + (size_t)b * NN * ND;
  const float* tgB = tgt + (size_t)b * NN * ND;

  for (int idx = lane; idx < NN * ND; idx += 64) inpS[idx] = inB[idx];
  for (int idx = lane; idx <= NN; idx += 64) { rowOwner[idx] = 0x7fffffff; uFree[idx] = 0.f; }
  __syncthreads();

  // this lane owns 0-indexed columns jA, jB  (1-indexed c1A, c1B)
  const int jA = 2 * lane;
  const int jB = 2 * lane + 1;
  const int c1A = jA + 1, c1B = jB + 1;

  float tA[ND], tB[ND];
  #pragma unroll
  for (int d = 0; d < ND; ++d) { tA[d] = tgB[jA * ND + d]; tB[d] = tgB[jB * ND + d]; }

  // build cost matrix C[i][j] = ||input_i - target_j||, fused column-min (CR)
  float vA = INFV, vB = INFV;  // column duals = column min
  int   rmA = 1,  rmB = 1;     // argmin row (first occurrence, 1-indexed)
  #pragma unroll 4
  for (int i = 0; i < NN; ++i) {
    float sA = 0.f, sB = 0.f;
    #pragma unroll
    for (int d = 0; d < ND; ++d) {
      float x = inpS[i * ND + d];
      float da = x - tA[d]; sA = fmaf(da, da, sA);
      float db = x - tB[d]; sB = fmaf(db, db, sB);
    }
    float cA = sqrtf(sA), cB = sqrtf(sB);
    ((float2*)(Csh + i * NN))[lane] = make_float2(cA, cB);
    if (cA < vA) { vA = cA; rmA = i + 1; }
    if (cB < vB) { vB = cB; rmB = i + 1; }
  }
  __syncthreads();

  // ---- column reduction: greedy match argmin rows, lowest column wins ----
  atomicMin(&rowOwner[rmA], c1A);
  atomicMin(&rowOwner[rmB], c1B);
  __syncthreads();

  int   pA = (rowOwner[rmA] == c1A) ? rmA : 0;  // matched row per column, 0 = free
  int   pB = (rowOwner[rmB] == c1B) ? rmB : 0;
  float uA = 0.f, uB = 0.f;   // dual of the row matched to col A/B
  int   wayA = 0, wayB = 0;

  // ---- reduction transfer (Jacobi, 2-wide paired reads) ----
  // All mins computed against v_old -> columns independent -> pair the
  // independent row reads for ILP. Feasibility: C - mu_i - v_new >=
  // C - mu_i - v_old >= 0; matched edges stay tight (C[i][j1] = v_old[j1]).
  {
    const float vOldA = vA, vOldB = vB;
    unsigned long long mtA = __ballot(pA != 0);
    unsigned long long mtB = __ballot(pB != 0);
    while (mtA | mtB) {
      int l1, s1;
      if (mtA) { l1 = __ffsll(mtA) - 1; mtA &= mtA - 1ull; s1 = 0; }
      else     { l1 = __ffsll(mtB) - 1; mtB &= mtB - 1ull; s1 = 1; }
      int i1 = rl_i(s1 ? pB : pA, l1);
      int l2 = -1, s2 = 0, i2 = 0;
      if (mtA)      { l2 = __ffsll(mtA) - 1; mtA &= mtA - 1ull; s2 = 0; }
      else if (mtB) { l2 = __ffsll(mtB) - 1; mtB &= mtB - 1ull; s2 = 1; }
      if (l2 >= 0) i2 = rl_i(s2 ? pB : pA, l2);

      const float2 c1 = ((const float2*)(Csh + (i1 - 1) * NN))[lane];
      float2 c2 = make_float2(0.f, 0.f);
      if (i2) c2 = ((const float2*)(Csh + (i2 - 1) * NN))[lane];

      float r1A = c1.x - vOldA, r1B = c1.y - vOldB;
      if (lane == l1) { if (s1) r1B = INFV; else r1A = INFV; }  // exclude j1
      float mu1 = wave_min_bcast(fminf(r1A, r1B));
      bool e1A = (lane == l1) && (s1 == 0);
      bool e1B = (lane == l1) && (s1 == 1);
      vA -= e1A ? mu1 : 0.f;   vB -= e1B ? mu1 : 0.f;
      uA  = e1A ? mu1 : uA;    uB  = e1B ? mu1 : uB;

      if (i2) {
        float r2A = c2.x - vOldA, r2B = c2.y - vOldB;
        if (lane == l2) { if (s2) r2B = INFV; else r2A = INFV; }
        float mu2 = wave_min_bcast(fminf(r2A, r2B));
        bool e2A = (lane == l2) && (s2 == 0);
        bool e2B = (lane == l2) && (s2 == 1);
        vA -= e2A ? mu2 : 0.f;   vB -= e2B ? mu2 : 0.f;
        uA  = e2A ? mu2 : uA;    uB  = e2B ? mu2 : uB;
      }
    }
  }

  // free rows after CR
  unsigned long long remLo = __ballot(rowOwner[1 + lane]  == 0x7fffffff);
  unsigned long long remHi = __ballot(rowOwner[65 + lane] == 0x7fffffff);

  // ---- augmenting row reduction: 6 bounded passes (no within-pass retry) ----
  #pragma unroll 1
  for (int pass = 0; pass < 6; ++pass) {
    unsigned long long inLo = remLo, inHi = remHi;
    unsigned long long outLo = 0ull, outHi = 0ull;
    while (inLo | inHi) {
      int i;
      if (inLo) { int t = __ffsll(inLo) - 1; inLo &= inLo - 1ull; i = t + 1; }
      else      { int t = __ffsll(inHi) - 1; inHi &= inHi - 1ull; i = t + 65; }

      const float2 c = ((const float2*)(Csh + (i - 1) * NN))[lane];
      float rcA = c.x - vA, rcB = c.y - vB;      // reduced costs
      float m1 = fminf(rcA, rcB), m2 = fmaxf(rcA, rcB);
      float candv = m1;
      bool  aMin  = (rcA <= rcB);                // prefer lower column on tie
      int   candc = aMin ? c1A : c1B;
      int   candp = aMin ? pA : pB;
      float candu = aMin ? uA : uB;
      wave_min2_bcast(m1, m2);                   // global (min1, min2)

      unsigned long long msk = __ballot(candv == m1);
      int l = __ffsll(msk) - 1;                  // lowest lane = lowest column
      int   j1   = rl_i(candc, l);               // three parallel readlanes
      int   i0   = rl_i(candp, l);
      float uOld = rl_f(candu, l);
      int owner = l, slot = (j1 - 1) & 1;

      float dv = m2 - m1;                        // >= 0
      bool selA = (lane == owner) && (slot == 0);
      bool selB = (lane == owner) && (slot == 1);
      vA -= selA ? dv : 0.f;   vB -= selB ? dv : 0.f;
      pA  = selA ? i  : pA;    pB  = selB ? i  : pB;
      uA  = selA ? m2 : uA;    uB  = selB ? m2 : uB;

      if (i0 != 0) {                             // stolen row -> next phase
        if (lane == 0) uFree[i0] = uOld;
        if (i0 <= 64) outLo |= 1ull << (i0 - 1);
        else          outHi |= 1ull << (i0 - 65);
      }
    }
    remLo = outLo; remHi = outHi;
  }
  unsigned long long dijLo = remLo, dijHi = remHi;

  // ---- LAZY Dijkstra augmentation, minimal serial chain ----
  while (dijLo | dijHi) {
    int i;
    if (dijLo) { int t = __ffsll(dijLo) - 1; dijLo &= dijLo - 1ull; i = t + 1; }
    else       { int t = __ffsll(dijHi) - 1; dijHi &= dijHi - 1ull; i = t + 65; }
    float uf = uFree[i];

    float dAllA = INFV, dAllB = INFV;    // true shortest-path distances
    float dLiveA = INFV, dLiveB = INFV;  // INF once used
    bool usedA = false, usedB = false;
    int   j0 = 0, i0 = i;
    float minVal = 0.f;
    float tshift = 0.f - uf;
    float tvA = tshift - vA, tvB = tshift - vB; // off-chain fold
    int   jfree = 0;

    for (int guard = 0; guard <= NN + 1; ++guard) {
      const float2 c = ((const float2*)(Csh + (i0 - 1) * NN))[lane];
      float curA = c.x + tvA;                   // 1 op after the load
      float curB = c.y + tvB;
      bool okA = !usedA && (curA < dAllA);
      bool okB = !usedB && (curB < dAllB);
      dAllA  = okA ? curA : dAllA;   dLiveA = okA ? curA : dLiveA;
      wayA   = okA ? j0 : wayA;
      dAllB  = okB ? curB : dAllB;   dLiveB = okB ? curB : dLiveB;
      wayB   = okB ? j0 : wayB;

      float candv = fminf(dLiveA, dLiveB);      // no selects on chain
      bool  aMin  = (dLiveA <= dLiveB);         // prefer lower column on tie
      int   candc = aMin ? c1A : c1B;
      int   candp = aMin ? pA : pB;
      float candu = aMin ? uA : uB;

      minVal = wave_min_bcast(candv);
      unsigned long long msk = __ballot(candv == minVal);
      int l = __ffsll(msk) - 1;
      int   j1  = rl_i(candc, l);               // parallel readlanes
      int   pj1 = rl_i(candp, l);
      float uj  = rl_f(candu, l);
      if (pj1 == 0) { jfree = j1; break; }

      bool nowA = (j1 == c1A), nowB = (j1 == c1B);
      usedA |= nowA;  usedB |= nowB;
      dLiveA = nowA ? INFV : dLiveA;            // hidden under next ds_read
      dLiveB = nowB ? INFV : dLiveB;
      tshift = minVal - uj;
      tvA = tshift - vA;  tvB = tshift - vB;    // hidden under next ds_read
      j0 = j1; i0 = pj1;
    }

    // vectorized dual update for tree columns (pre-augmentation)
    {
      float adjA = dAllA - minVal;              // <= 0 for used columns
      float adjB = dAllB - minVal;
      vA += usedA ? adjA : 0.f;   uA -= usedA ? adjA : 0.f;
      vB += usedB ? adjB : 0.f;   uB -= usedB ? adjB : 0.f;
    }
    float ucur = uf + minVal;                   // new dual of the start row

    // augment along way[] chain; transfer row + its dual between columns
    int jj = jfree;
    for (int g = 0; g < NN + 1 && jj != 0; ++g) {
      int owner = (jj - 1) >> 1, slot = (jj - 1) & 1;
      int wj = slot ? rl_i(wayB, owner) : rl_i(wayA, owner);
      int pnew; float unew;
      if (wj == 0) { pnew = i; unew = ucur; }
      else {
        int o2 = (wj - 1) >> 1, s2 = (wj - 1) & 1;
        pnew = s2 ? rl_i(pB, o2) : rl_i(pA, o2);
        unew = s2 ? rl_f(uB, o2) : rl_f(uA, o2);
      }
      bool selA = (lane == owner) && (slot == 0);
      bool selB = (lane == owner) && (slot == 1);
      pA = selA ? pnew : pA;  uA = selA ? unew : uA;
      pB = selB ? pnew : pB;  uB = selB ? unew : uB;
      jj = wj;
    }
  }

  // loss: column j (0-idx) is matched to row r = p-1; d = input[r] - target[j]
  int rA = pA - 1;
  int rB = pB - 1;
  float acc[ND];
  #pragma unroll
  for (int d = 0; d < ND; ++d) {
    float dA = inpS[rA * ND + d] - tA[d];
    float dB = inpS[rB * ND + d] - tB[d];
    if (d == 4) { dA = wrap_phi(dA); dB = wrap_phi(dB); }
    acc[d] = dA * dA + dB * dB;
  }
  #pragma unroll
  for (int d = 0; d < ND; ++d) {
    float s = acc[d];
    #pragma unroll
    for (int off = 32; off > 0; off >>= 1) s += __shfl_xor(s, off);
    if (lane == 0) atomicAdd(&sums[d], s);
  }
}

__global__ void set2set_finalize(const float* __restrict__ sums, float* __restrict__ out) {
  const float inv = 1.0f / (128.0f * 128.0f);
  float x  = sums[0] * inv;
  float y  = sums[1] * inv;
  float E  = sums[2] * inv;
  float th = sums[3] * inv;
  float ph = sums[4] * inv;
  out[1] = x; out[2] = y; out[3] = E; out[4] = th; out[5] = ph;
  out[0] = x + y + E + th + ph;
}

extern "C" void kernel_launch(void* const* d_in, const int* in_sizes, int n_in,
                              void* d_out, int out_size, void* d_ws, size_t ws_size,
                              hipStream_t stream) {
  const float* inp = (const float*)d_in[0];
  const float* tgt = (const float*)d_in[1];
  float* out  = (float*)d_out;
  float* sums = (float*)d_ws;

  hipMemsetAsync(sums, 0, ND * sizeof(float), stream);
  set2set_hungarian<<<dim3(NB), dim3(64), 0, stream>>>(inp, tgt, sums);
  set2set_finalize<<<dim3(1), dim3(1), 0, stream>>>(sums, out);
}